// Round 1
// baseline (1327.429 us; speedup 1.0000x reference)
//
#include <hip/hip_runtime.h>

// Problem constants (B=2, S=2048, D=1024, H=16, hd=64)
#define S_LEN   2048
#define D_MODEL 1024
#define N_HEADS 16
#define HEAD_DIM 64

// ---------------------------------------------------------------------------
// GEMM: C[m][n] = sum_k A[m][k] * W[n][k] (+ bias[n])
// A: M x K row-major, W: N x K row-major (nn.Linear weight), C: M x N.
// 64x64 tile, BK=16, 256 threads, 4x4 micro-tile per thread.
// LDS layout [k][m] with +4 pad: b128 reads, <=2-way conflicts (free).
// ---------------------------------------------------------------------------
template <bool HAS_BIAS>
__global__ __launch_bounds__(256) void gemm_bt(const float* __restrict__ A,
                                               const float* __restrict__ W,
                                               const float* __restrict__ bias,
                                               float* __restrict__ C,
                                               int M, int N, int K) {
    __shared__ float As[16][68];
    __shared__ float Ws[16][68];

    const int tid = threadIdx.x;
    const int tx = tid & 15;        // 0..15 -> n micro
    const int ty = tid >> 4;        // 0..15 -> m micro
    const int mBase = blockIdx.y * 64;
    const int nBase = blockIdx.x * 64;

    const int lr  = tid >> 2;         // 0..63  row within tile for staging
    const int lk4 = (tid & 3) << 2;   // 0,4,8,12 k-offset for staging

    float acc[4][4] = {};

    for (int k0 = 0; k0 < K; k0 += 16) {
        // global loads (coalesced float4 along k)
        const float4 a4 = *(const float4*)(A + (size_t)(mBase + lr) * K + k0 + lk4);
        const float4 w4 = *(const float4*)(W + (size_t)(nBase + lr) * K + k0 + lk4);
        __syncthreads();   // previous iteration finished reading LDS
        As[lk4 + 0][lr] = a4.x; As[lk4 + 1][lr] = a4.y;
        As[lk4 + 2][lr] = a4.z; As[lk4 + 3][lr] = a4.w;
        Ws[lk4 + 0][lr] = w4.x; Ws[lk4 + 1][lr] = w4.y;
        Ws[lk4 + 2][lr] = w4.z; Ws[lk4 + 3][lr] = w4.w;
        __syncthreads();

#pragma unroll
        for (int kk = 0; kk < 16; ++kk) {
            const float4 av = *(const float4*)&As[kk][ty << 2];  // 16B aligned (68*4 % 16 == 0)
            const float4 wv = *(const float4*)&Ws[kk][tx << 2];
            const float a[4] = {av.x, av.y, av.z, av.w};
            const float w[4] = {wv.x, wv.y, wv.z, wv.w};
#pragma unroll
            for (int i = 0; i < 4; ++i)
#pragma unroll
                for (int j = 0; j < 4; ++j)
                    acc[i][j] += a[i] * w[j];
        }
    }

#pragma unroll
    for (int i = 0; i < 4; ++i) {
        const int m = mBase + (ty << 2) + i;
        const int n = nBase + (tx << 2);
        float4 o4 = make_float4(acc[i][0], acc[i][1], acc[i][2], acc[i][3]);
        if (HAS_BIAS) {
            o4.x += bias[n + 0]; o4.y += bias[n + 1];
            o4.z += bias[n + 2]; o4.w += bias[n + 3];
        }
        *(float4*)(C + (size_t)m * N + n) = o4;
    }
}

// ---------------------------------------------------------------------------
// Flash-style causal attention per (b, h, 64-query tile).
// Q/K/V per head are contiguous (S, 64) row-major chunks (the module's direct
// flat reshape). Logits scaled by 1/hd (module divides by head_dim, not sqrt).
// Output written in (B, S, H*hd) layout so the O-proj GEMM reads it flat.
// ---------------------------------------------------------------------------
__global__ __launch_bounds__(256) void attn_kernel(const float* __restrict__ Q,
                                                   const float* __restrict__ K,
                                                   const float* __restrict__ V,
                                                   float* __restrict__ O) {
    const int qt = blockIdx.x;   // 0..31
    const int h  = blockIdx.y;   // 0..15
    const int b  = blockIdx.z;   // 0..1
    const int tid = threadIdx.x;
    const int tx = tid & 15;
    const int ty = tid >> 4;

    __shared__ float Qs[64][65];
    __shared__ float Ks[64][65];
    __shared__ float Vs[64][65];
    __shared__ float Ps[64][65];

    const size_t headOff = (size_t)b * S_LEN * D_MODEL + (size_t)h * S_LEN * HEAD_DIM;
    const float* Qh = Q + headOff;
    const float* Kh = K + headOff;
    const float* Vh = V + headOff;
    const int qBase = qt * 64;

    // stage Q tile (scalar LDS stores: pad-65 keeps conflicts <=2-way)
#pragma unroll
    for (int it = 0; it < 4; ++it) {
        const int idx = tid + it * 256;       // 0..1023
        const int rr = idx >> 4;              // 0..63
        const int cc = (idx & 15) << 2;       // 0..60
        const float4 q4 = *(const float4*)(Qh + (size_t)(qBase + rr) * HEAD_DIM + cc);
        Qs[rr][cc + 0] = q4.x; Qs[rr][cc + 1] = q4.y;
        Qs[rr][cc + 2] = q4.z; Qs[rr][cc + 3] = q4.w;
    }

    float m_i[4], l_i[4], o[4][4];
#pragma unroll
    for (int i = 0; i < 4; ++i) {
        m_i[i] = -1e30f; l_i[i] = 0.f;
#pragma unroll
        for (int j = 0; j < 4; ++j) o[i][j] = 0.f;
    }

    const float scale = 1.0f / (float)HEAD_DIM;

    for (int kt = 0; kt <= qt; ++kt) {
        const int kBase = kt * 64;
        __syncthreads();   // previous iteration done with Ks/Vs/Ps (covers Qs 1st iter)
#pragma unroll
        for (int it = 0; it < 4; ++it) {
            const int idx = tid + it * 256;
            const int rr = idx >> 4;
            const int cc = (idx & 15) << 2;
            const float4 k4 = *(const float4*)(Kh + (size_t)(kBase + rr) * HEAD_DIM + cc);
            Ks[rr][cc + 0] = k4.x; Ks[rr][cc + 1] = k4.y;
            Ks[rr][cc + 2] = k4.z; Ks[rr][cc + 3] = k4.w;
            const float4 v4 = *(const float4*)(Vh + (size_t)(kBase + rr) * HEAD_DIM + cc);
            Vs[rr][cc + 0] = v4.x; Vs[rr][cc + 1] = v4.y;
            Vs[rr][cc + 2] = v4.z; Vs[rr][cc + 3] = v4.w;
        }
        __syncthreads();

        // S = Q . K^T  (64x64x64)
        float s[4][4] = {};
#pragma unroll 16
        for (int d = 0; d < 64; ++d) {
            float a[4], w[4];
#pragma unroll
            for (int i = 0; i < 4; ++i) a[i] = Qs[(ty << 2) + i][d];  // broadcast/2-way
#pragma unroll
            for (int j = 0; j < 4; ++j) w[j] = Ks[(tx << 2) + j][d];  // 2-way
#pragma unroll
            for (int i = 0; i < 4; ++i)
#pragma unroll
                for (int j = 0; j < 4; ++j)
                    s[i][j] += a[i] * w[j];
        }

        // scale by 1/hd, causal mask (diagonal tile only)
        if (kt == qt) {
#pragma unroll
            for (int i = 0; i < 4; ++i)
#pragma unroll
                for (int j = 0; j < 4; ++j) {
                    const bool masked = (kBase + (tx << 2) + j) > (qBase + (ty << 2) + i);
                    s[i][j] = masked ? -1e30f : s[i][j] * scale;
                }
        } else {
#pragma unroll
            for (int i = 0; i < 4; ++i)
#pragma unroll
                for (int j = 0; j < 4; ++j) s[i][j] *= scale;
        }

        // online softmax (row stats across the 16 tx lanes of each row)
#pragma unroll
        for (int i = 0; i < 4; ++i) {
            float mx = fmaxf(fmaxf(s[i][0], s[i][1]), fmaxf(s[i][2], s[i][3]));
#pragma unroll
            for (int off = 1; off < 16; off <<= 1) mx = fmaxf(mx, __shfl_xor(mx, off));
            const float m_new = fmaxf(m_i[i], mx);
            const float alpha = __expf(m_i[i] - m_new);
            float rs = 0.f;
#pragma unroll
            for (int j = 0; j < 4; ++j) { s[i][j] = __expf(s[i][j] - m_new); rs += s[i][j]; }
#pragma unroll
            for (int off = 1; off < 16; off <<= 1) rs += __shfl_xor(rs, off);
            l_i[i] = l_i[i] * alpha + rs;
            m_i[i] = m_new;
#pragma unroll
            for (int j = 0; j < 4; ++j) o[i][j] *= alpha;
#pragma unroll
            for (int j = 0; j < 4; ++j) Ps[(ty << 2) + i][(tx << 2) + j] = s[i][j];
        }
        __syncthreads();

        // O += P . V  (64x64x64)
#pragma unroll 16
        for (int c = 0; c < 64; ++c) {
            float pi[4], vj[4];
#pragma unroll
            for (int j = 0; j < 4; ++j) vj[j] = Vs[c][(tx << 2) + j];     // 2-way
#pragma unroll
            for (int i = 0; i < 4; ++i) pi[i] = Ps[(ty << 2) + i][c];     // broadcast
#pragma unroll
            for (int i = 0; i < 4; ++i)
#pragma unroll
                for (int j = 0; j < 4; ++j)
                    o[i][j] += pi[i] * vj[j];
        }
    }

    // normalize + write in (B, S, H*hd) layout: out[b, q, h*64 + d]
    float* Ob = O + (size_t)b * S_LEN * D_MODEL + (size_t)h * HEAD_DIM;
#pragma unroll
    for (int i = 0; i < 4; ++i) {
        const int q = qBase + (ty << 2) + i;
        const float inv = 1.0f / l_i[i];
        const float4 o4 = make_float4(o[i][0] * inv, o[i][1] * inv,
                                      o[i][2] * inv, o[i][3] * inv);
        *(float4*)(Ob + (size_t)q * D_MODEL + (tx << 2)) = o4;
    }
}

// ---------------------------------------------------------------------------
extern "C" void kernel_launch(void* const* d_in, const int* in_sizes, int n_in,
                              void* d_out, int out_size, void* d_ws, size_t ws_size,
                              hipStream_t stream) {
    const float* hs = (const float*)d_in[0];
    const float* Wq = (const float*)d_in[1];
    const float* Wk = (const float*)d_in[2];
    const float* Wv = (const float*)d_in[3];
    const float* Wo = (const float*)d_in[4];
    const float* bo = (const float*)d_in[5];
    float* out = (float*)d_out;

    const size_t BSD = (size_t)2 * S_LEN * D_MODEL;  // 4M floats
    float* Qf = (float*)d_ws;
    float* Kf = Qf + BSD;
    float* Vf = Kf + BSD;
    float* Cf = Vf + BSD;   // attention context in (B,S,D) transposed-head layout

    const int M = 2 * S_LEN;   // 4096
    const int N = D_MODEL;     // 1024
    const int Kd = D_MODEL;    // 1024

    dim3 gblk(N / 64, M / 64);
    dim3 tblk(256);

    gemm_bt<false><<<gblk, tblk, 0, stream>>>(hs, Wq, nullptr, Qf, M, N, Kd);
    gemm_bt<false><<<gblk, tblk, 0, stream>>>(hs, Wk, nullptr, Kf, M, N, Kd);
    gemm_bt<false><<<gblk, tblk, 0, stream>>>(hs, Wv, nullptr, Vf, M, N, Kd);

    attn_kernel<<<dim3(32, N_HEADS, 2), tblk, 0, stream>>>(Qf, Kf, Vf, Cf);

    gemm_bt<true><<<gblk, tblk, 0, stream>>>(Cf, Wo, bo, out, M, N, Kd);
}

// Round 2
// 346.249 us; speedup vs baseline: 3.8337x; 3.8337x over previous
//
#include <hip/hip_runtime.h>

#define S_LEN   2048
#define D_MODEL 1024
#define N_HEADS 16
#define HEAD_DIM 64

typedef unsigned short u16;
typedef float  floatx4 __attribute__((ext_vector_type(4)));
typedef short  bf16x8  __attribute__((ext_vector_type(8)));

__device__ __forceinline__ u16 f2bf(float f) {
    unsigned int u = __float_as_uint(f);
    u += 0x7FFF + ((u >> 16) & 1);      // RNE
    return (u16)(u >> 16);
}

// ---------------------------------------------------------------------------
// fp32 -> bf16 cast, 8 elements/thread
// ---------------------------------------------------------------------------
__global__ __launch_bounds__(256) void cast_kernel(const float* __restrict__ src,
                                                   u16* __restrict__ dst, int n) {
    int i = (blockIdx.x * 256 + threadIdx.x) * 8;
    if (i >= n) return;
    float4 a = *(const float4*)(src + i);
    float4 b = *(const float4*)(src + i + 4);
    uint4 o;
    o.x = (unsigned)f2bf(a.x) | ((unsigned)f2bf(a.y) << 16);
    o.y = (unsigned)f2bf(a.z) | ((unsigned)f2bf(a.w) << 16);
    o.z = (unsigned)f2bf(b.x) | ((unsigned)f2bf(b.y) << 16);
    o.w = (unsigned)f2bf(b.z) | ((unsigned)f2bf(b.w) << 16);
    *(uint4*)(dst + i) = o;
}

__device__ __forceinline__ void store_out(float* p, float v) { *p = v; }
__device__ __forceinline__ void store_out(u16* p, float v)   { *p = f2bf(v); }

// ---------------------------------------------------------------------------
// bf16 MFMA GEMM: C[m][n] = sum_k A[m][k]*W[n][k] (+bias). 128x128 tile, BK=32.
// 4 waves in 2x2; each wave: 4x4 grid of 16x16 MFMA tiles.
// LDS row stride 40 ushorts (80B): frag reads/writes hit 8 lanes/bank-group
// (minimum phases for b128 -> conflict-free).
// ---------------------------------------------------------------------------
template <typename OutT, bool HAS_BIAS>
__global__ __launch_bounds__(256) void gemm_mfma(const u16* __restrict__ A,
                                                 const u16* __restrict__ W,
                                                 const float* __restrict__ bias,
                                                 OutT* __restrict__ C,
                                                 int M, int N, int K) {
    __shared__ u16 As[128 * 40];
    __shared__ u16 Ws[128 * 40];

    const int tid  = threadIdx.x;
    const int lane = tid & 63;
    const int wv   = tid >> 6;
    const int wm   = wv & 1, wn = wv >> 1;
    const int l15  = lane & 15, quad = lane >> 4;
    const int mBase = blockIdx.y * 128;
    const int nBase = blockIdx.x * 128;

    const int r0 = tid >> 2;       // staging row 0..63 (and +64)
    const int c0 = tid & 3;        // staging 16B chunk 0..3

    floatx4 acc[4][4];
#pragma unroll
    for (int i = 0; i < 4; ++i)
#pragma unroll
        for (int j = 0; j < 4; ++j) acc[i][j] = (floatx4)(0.0f);

    for (int k0 = 0; k0 < K; k0 += 32) {
        const float4 a0 = *(const float4*)(A + (size_t)(mBase + r0)      * K + k0 + c0 * 8);
        const float4 a1 = *(const float4*)(A + (size_t)(mBase + r0 + 64) * K + k0 + c0 * 8);
        const float4 w0 = *(const float4*)(W + (size_t)(nBase + r0)      * K + k0 + c0 * 8);
        const float4 w1 = *(const float4*)(W + (size_t)(nBase + r0 + 64) * K + k0 + c0 * 8);
        __syncthreads();
        *(float4*)&As[r0 * 40 + c0 * 8]        = a0;
        *(float4*)&As[(r0 + 64) * 40 + c0 * 8] = a1;
        *(float4*)&Ws[r0 * 40 + c0 * 8]        = w0;
        *(float4*)&Ws[(r0 + 64) * 40 + c0 * 8] = w1;
        __syncthreads();

        bf16x8 af[4], bfr[4];
#pragma unroll
        for (int mt = 0; mt < 4; ++mt)
            af[mt] = *(const bf16x8*)&As[(wm * 64 + mt * 16 + l15) * 40 + quad * 8];
#pragma unroll
        for (int nt = 0; nt < 4; ++nt)
            bfr[nt] = *(const bf16x8*)&Ws[(wn * 64 + nt * 16 + l15) * 40 + quad * 8];
#pragma unroll
        for (int mt = 0; mt < 4; ++mt)
#pragma unroll
            for (int nt = 0; nt < 4; ++nt)
                acc[mt][nt] = __builtin_amdgcn_mfma_f32_16x16x32_bf16(af[mt], bfr[nt], acc[mt][nt], 0, 0, 0);
    }

#pragma unroll
    for (int mt = 0; mt < 4; ++mt)
#pragma unroll
        for (int nt = 0; nt < 4; ++nt) {
            const int col = nBase + wn * 64 + nt * 16 + l15;
            const float bv = HAS_BIAS ? bias[col] : 0.0f;
#pragma unroll
            for (int r = 0; r < 4; ++r) {
                const int row = mBase + wm * 64 + mt * 16 + quad * 4 + r;
                store_out(&C[(size_t)row * N + col], acc[mt][nt][r] + bv);
            }
        }
}

// ---------------------------------------------------------------------------
// MFMA flash attention. Block = (q-tile of 64, h, b), 4 waves x 16 queries.
// Q/K row-major in LDS (stride 72), V transposed (d-major) so PV B-operand
// reads are contiguous. P: C-layout scalar writes -> A-layout b128 reads.
// Logits scaled by 1/hd (module semantics), computed in log2 domain.
// ---------------------------------------------------------------------------
__global__ __launch_bounds__(256) void attn_mfma(const u16* __restrict__ Q,
                                                 const u16* __restrict__ K,
                                                 const u16* __restrict__ V,
                                                 u16* __restrict__ Ctx) {
    const int qt = 31 - blockIdx.x;     // heavy blocks first
    const int h  = blockIdx.y;
    const int b  = blockIdx.z;

    __shared__ u16 Qs[64 * 72];
    __shared__ u16 Ks[64 * 72];
    __shared__ u16 Vt[64 * 72];         // Vt[d][key]
    __shared__ u16 Ps[4][16 * 72];      // per-wave P tile

    const int tid  = threadIdx.x;
    const int lane = tid & 63;
    const int wv   = tid >> 6;
    const int l15  = lane & 15, quad = lane >> 4;

    const size_t headOff = ((size_t)b * N_HEADS + h) * S_LEN * HEAD_DIM;
    const u16* Qh = Q + headOff;
    const u16* Kh = K + headOff;
    const u16* Vh = V + headOff;
    const int qBase = qt * 64;

    // stage Q (once): chunk = row*8 + c
#pragma unroll
    for (int it = 0; it < 2; ++it) {
        const int chunk = tid + it * 256;
        const int row = chunk >> 3, c = chunk & 7;
        *(float4*)&Qs[row * 72 + c * 8] =
            *(const float4*)(Qh + (size_t)(qBase + row) * 64 + c * 8);
    }

    float m_r[4], l_r[4];
    floatx4 o[4];
#pragma unroll
    for (int r = 0; r < 4; ++r) { m_r[r] = -1e30f; l_r[r] = 0.0f; }
#pragma unroll
    for (int nt = 0; nt < 4; ++nt) o[nt] = (floatx4)(0.0f);

    const float sl2 = 1.44269504088896f / (float)HEAD_DIM;  // log2e / hd

    const int vKey = tid & 63;          // V staging: lane-major over keys
    const int vC0  = tid >> 6;          // 0..3, handles c and c+4

    for (int kt = 0; kt <= qt; ++kt) {
        const int kBase = kt * 64;

        // prefetch globals for this tile
        float4 kreg[2], vreg[2];
#pragma unroll
        for (int it = 0; it < 2; ++it) {
            const int chunk = tid + it * 256;
            const int row = chunk >> 3, c = chunk & 7;
            kreg[it] = *(const float4*)(Kh + (size_t)(kBase + row) * 64 + c * 8);
        }
#pragma unroll
        for (int it = 0; it < 2; ++it) {
            const int cc = vC0 + it * 4;
            vreg[it] = *(const float4*)(Vh + (size_t)(kBase + vKey) * 64 + cc * 8);
        }

        __syncthreads();   // prev iteration done reading Ks/Vt
#pragma unroll
        for (int it = 0; it < 2; ++it) {
            const int chunk = tid + it * 256;
            const int row = chunk >> 3, c = chunk & 7;
            *(float4*)&Ks[row * 72 + c * 8] = kreg[it];
        }
#pragma unroll
        for (int it = 0; it < 2; ++it) {
            const int cc = vC0 + it * 4;
            const u16* vs = (const u16*)&vreg[it];
#pragma unroll
            for (int j = 0; j < 8; ++j)
                Vt[(cc * 8 + j) * 72 + vKey] = vs[j];   // banks spread over key -> ~free
        }
        __syncthreads();

        // S = Q . K^T  (wave: 16 x 64, 8 MFMAs)
        bf16x8 qa[2];
#pragma unroll
        for (int ks = 0; ks < 2; ++ks)
            qa[ks] = *(const bf16x8*)&Qs[(wv * 16 + l15) * 72 + ks * 32 + quad * 8];

        floatx4 s[4];
#pragma unroll
        for (int nt = 0; nt < 4; ++nt) {
            s[nt] = (floatx4)(0.0f);
#pragma unroll
            for (int ks = 0; ks < 2; ++ks) {
                const bf16x8 kb = *(const bf16x8*)&Ks[(nt * 16 + l15) * 72 + ks * 32 + quad * 8];
                s[nt] = __builtin_amdgcn_mfma_f32_16x16x32_bf16(qa[ks], kb, s[nt], 0, 0, 0);
            }
        }

        // online softmax per row r (row = quad*4 + r), cols across l15 x 4 nt
        const bool diag = (kt == qt);
#pragma unroll
        for (int r = 0; r < 4; ++r) {
            const int rowG = qBase + wv * 16 + quad * 4 + r;
            float sv[4];
#pragma unroll
            for (int nt = 0; nt < 4; ++nt) {
                sv[nt] = s[nt][r] * sl2;
                if (diag && (kBase + nt * 16 + l15 > rowG)) sv[nt] = -3.0e38f;
            }
            float mx = fmaxf(fmaxf(sv[0], sv[1]), fmaxf(sv[2], sv[3]));
#pragma unroll
            for (int off = 1; off < 16; off <<= 1) mx = fmaxf(mx, __shfl_xor(mx, off));
            const float mnew  = fmaxf(m_r[r], mx);
            const float alpha = exp2f(m_r[r] - mnew);
            float rs = 0.0f;
#pragma unroll
            for (int nt = 0; nt < 4; ++nt) {
                const float p = exp2f(sv[nt] - mnew);
                rs += p;
                Ps[wv][(quad * 4 + r) * 72 + nt * 16 + l15] = f2bf(p);
            }
#pragma unroll
            for (int off = 1; off < 16; off <<= 1) rs += __shfl_xor(rs, off);
            l_r[r] = l_r[r] * alpha + rs;
            m_r[r] = mnew;
#pragma unroll
            for (int nt = 0; nt < 4; ++nt) o[nt][r] *= alpha;
        }

        // O += P . V  (wave-private P: in-wave DS ordering, no barrier needed)
        bf16x8 pa[2];
#pragma unroll
        for (int ks = 0; ks < 2; ++ks)
            pa[ks] = *(const bf16x8*)&Ps[wv][l15 * 72 + ks * 32 + quad * 8];
#pragma unroll
        for (int nt = 0; nt < 4; ++nt) {
#pragma unroll
            for (int ks = 0; ks < 2; ++ks) {
                const bf16x8 vb = *(const bf16x8*)&Vt[(nt * 16 + l15) * 72 + ks * 32 + quad * 8];
                o[nt] = __builtin_amdgcn_mfma_f32_16x16x32_bf16(pa[ks], vb, o[nt], 0, 0, 0);
            }
        }
    }

    // epilogue: normalize, write Ctx in (B, S, H*hd) layout
    u16* Cb = Ctx + (size_t)b * S_LEN * D_MODEL + (size_t)h * HEAD_DIM;
#pragma unroll
    for (int r = 0; r < 4; ++r) {
        const float inv = 1.0f / l_r[r];
        const int row = qBase + wv * 16 + quad * 4 + r;
#pragma unroll
        for (int nt = 0; nt < 4; ++nt)
            Cb[(size_t)row * D_MODEL + nt * 16 + l15] = f2bf(o[nt][r] * inv);
    }
}

// ---------------------------------------------------------------------------
extern "C" void kernel_launch(void* const* d_in, const int* in_sizes, int n_in,
                              void* d_out, int out_size, void* d_ws, size_t ws_size,
                              hipStream_t stream) {
    const float* hs = (const float*)d_in[0];
    const float* Wq = (const float*)d_in[1];
    const float* Wk = (const float*)d_in[2];
    const float* Wv = (const float*)d_in[3];
    const float* Wo = (const float*)d_in[4];
    const float* bo = (const float*)d_in[5];
    float* out = (float*)d_out;

    const size_t NHS = (size_t)2 * S_LEN * D_MODEL;  // 4M elements
    const size_t NW  = (size_t)D_MODEL * D_MODEL;    // 1M elements

    u16* hsb = (u16*)d_ws;
    u16* Wqb = hsb + NHS;
    u16* Wkb = Wqb + NW;
    u16* Wvb = Wkb + NW;
    u16* Wob = Wvb + NW;
    u16* Qb  = Wob + NW;
    u16* Kb  = Qb + NHS;
    u16* Vb  = Kb + NHS;
    u16* Cxb = Vb + NHS;

    const int M = 2 * S_LEN;   // 4096
    const int N = D_MODEL;     // 1024
    const int Kd = D_MODEL;    // 1024

    cast_kernel<<<(int)(NHS / 2048), 256, 0, stream>>>(hs, hsb, (int)NHS);
    cast_kernel<<<(int)(NW / 2048), 256, 0, stream>>>(Wq, Wqb, (int)NW);
    cast_kernel<<<(int)(NW / 2048), 256, 0, stream>>>(Wk, Wkb, (int)NW);
    cast_kernel<<<(int)(NW / 2048), 256, 0, stream>>>(Wv, Wvb, (int)NW);
    cast_kernel<<<(int)(NW / 2048), 256, 0, stream>>>(Wo, Wob, (int)NW);

    dim3 gblk(N / 128, M / 128);
    gemm_mfma<u16, false><<<gblk, 256, 0, stream>>>(hsb, Wqb, nullptr, Qb, M, N, Kd);
    gemm_mfma<u16, false><<<gblk, 256, 0, stream>>>(hsb, Wkb, nullptr, Kb, M, N, Kd);
    gemm_mfma<u16, false><<<gblk, 256, 0, stream>>>(hsb, Wvb, nullptr, Vb, M, N, Kd);

    attn_mfma<<<dim3(32, N_HEADS, 2), 256, 0, stream>>>(Qb, Kb, Vb, Cxb);

    gemm_mfma<float, true><<<gblk, 256, 0, stream>>>(Cxb, Wob, bo, out, M, N, Kd);
}

// Round 4
// 197.974 us; speedup vs baseline: 6.7051x; 1.7490x over previous
//
#include <hip/hip_runtime.h>

#define S_LEN   2048
#define D_MODEL 1024
#define N_HEADS 16
#define HEAD_DIM 64

typedef unsigned short u16;
typedef float  floatx4 __attribute__((ext_vector_type(4)));
typedef short  bf16x8  __attribute__((ext_vector_type(8)));

__device__ __forceinline__ u16 f2bf(float f) {
    unsigned int u = __float_as_uint(f);
    u += 0x7FFF + ((u >> 16) & 1);      // RNE
    return (u16)(u >> 16);
}
__device__ __forceinline__ unsigned pack2bf(float a, float b) {
    return (unsigned)f2bf(a) | ((unsigned)f2bf(b) << 16);
}

// global -> LDS direct copy, 16B/lane. LDS dest = wave-uniform base + lane*16.
__device__ __forceinline__ void gload_lds16(const void* g, void* l) {
    __builtin_amdgcn_global_load_lds(
        reinterpret_cast<const __attribute__((address_space(1))) unsigned int*>(
            reinterpret_cast<uintptr_t>(g)),
        reinterpret_cast<__attribute__((address_space(3))) unsigned int*>(
            reinterpret_cast<uintptr_t>(l)),
        16, 0, 0);
}

// ---------------------------------------------------------------------------
// fp32 -> bf16 casts
// ---------------------------------------------------------------------------
__global__ __launch_bounds__(256) void cast_hs(const float* __restrict__ src,
                                               u16* __restrict__ dst) {
    const int i = (blockIdx.x * 256 + threadIdx.x) * 8;
    const float4 a = *(const float4*)(src + i);
    const float4 b = *(const float4*)(src + i + 4);
    uint4 o;
    o.x = pack2bf(a.x, a.y); o.y = pack2bf(a.z, a.w);
    o.z = pack2bf(b.x, b.y); o.w = pack2bf(b.z, b.w);
    *(uint4*)(dst + i) = o;
}

__global__ __launch_bounds__(256) void cast_w(const float* __restrict__ w0,
                                              const float* __restrict__ w1,
                                              const float* __restrict__ w2,
                                              const float* __restrict__ w3,
                                              u16* __restrict__ dst) {
    const float* srcs[4] = {w0, w1, w2, w3};
    const float* src = srcs[blockIdx.y];
    u16* o = dst + (size_t)blockIdx.y * (D_MODEL * D_MODEL);
    const int i = (blockIdx.x * 256 + threadIdx.x) * 8;
    const float4 a = *(const float4*)(src + i);
    const float4 b = *(const float4*)(src + i + 4);
    uint4 v;
    v.x = pack2bf(a.x, a.y); v.y = pack2bf(a.z, a.w);
    v.z = pack2bf(b.x, b.y); v.w = pack2bf(b.z, b.w);
    *(uint4*)(o + i) = v;
}

// ---------------------------------------------------------------------------
// Per-head V transpose. The module's flat view makes head (b,h) a CONTIGUOUS
// (2048 s, 64 d) chunk at Vf + (b*16+h)*131072. Transpose to Vt[bh][d][s].
// LDS tile 128 s x 64 d in 4B slots, stride 133 -> <=2-way write conflicts,
// 4-way read (1.58x). All global traffic float4-coalesced.
// ---------------------------------------------------------------------------
__global__ __launch_bounds__(256) void vtrans(const u16* __restrict__ Vf,
                                              u16* __restrict__ Vt) {
    __shared__ unsigned T[64 * 133];
    const int bh = blockIdx.y;            // 0..31
    const int sBase = blockIdx.x * 128;   // 16 chunks of 128 tokens
    const u16* src = Vf + (size_t)bh * (S_LEN * HEAD_DIM) + (size_t)sBase * HEAD_DIM;
    u16* dst = Vt + (size_t)bh * (S_LEN * HEAD_DIM) + sBase;
    const int tid = threadIdx.x;

#pragma unroll
    for (int it = 0; it < 4; ++it) {
        const int idx = it * 256 + tid;   // 0..1023
        const int row = idx >> 3, ch = idx & 7;
        const float4 v4 = *(const float4*)(src + row * 64 + ch * 8);
        const u16* vs = (const u16*)&v4;
#pragma unroll
        for (int j = 0; j < 8; ++j) T[(ch * 8 + j) * 133 + row] = vs[j];
    }
    __syncthreads();
#pragma unroll
    for (int it = 0; it < 4; ++it) {
        const int idx = it * 256 + tid;   // 0..1023
        const int d = idx >> 4, sc = idx & 15;
        union { u16 u[8]; float4 f; } tmp;
#pragma unroll
        for (int j = 0; j < 8; ++j) tmp.u[j] = (u16)T[d * 133 + sc * 8 + j];
        *(float4*)(dst + (size_t)d * S_LEN + sc * 8) = tmp.f;
    }
}

// ---------------------------------------------------------------------------
// Fused QKV GEMM, m97 structure: 128x128 tile, BK=32, global_load_lds staging,
// XOR-swizzled unpadded LDS. which = blockIdx.x>>3 selects Q/K/V.
// Q output pre-scaled by log2e/64. All outputs standard (row, col) layout.
// ---------------------------------------------------------------------------
__global__ __launch_bounds__(256) void gemm_qkv(const u16* __restrict__ A,
                                                const u16* __restrict__ Wq,
                                                const u16* __restrict__ Wk,
                                                const u16* __restrict__ Wv,
                                                u16* __restrict__ Qo,
                                                u16* __restrict__ Ko,
                                                u16* __restrict__ Vfo) {
    __shared__ u16 As[8 * 512];
    __shared__ u16 Ws[8 * 512];

    const int which = blockIdx.x >> 3;
    const int nBase = (blockIdx.x & 7) * 128;
    const int mBase = blockIdx.y * 128;
    const u16* W = which == 0 ? Wq : which == 1 ? Wk : Wv;

    const int tid = threadIdx.x, lane = tid & 63, wv = tid >> 6;
    const int l15 = lane & 15, quad = lane >> 4;
    const int wm = wv & 1, wn = wv >> 1;
    const int srow = lane >> 2;                        // 0..15
    const int gch  = (lane & 3) ^ ((lane >> 3) & 3);   // swizzled src chunk
    const int swz  = (l15 >> 1) & 3;                   // read-side swizzle

    floatx4 acc[4][4];
#pragma unroll
    for (int i = 0; i < 4; ++i)
#pragma unroll
        for (int j = 0; j < 4; ++j) acc[i][j] = (floatx4)(0.0f);

    for (int k0 = 0; k0 < D_MODEL; k0 += 32) {
        __syncthreads();
#pragma unroll
        for (int t = 0; t < 2; ++t) {
            const int ci = wv * 2 + t;
            gload_lds16(A + (size_t)(mBase + ci * 16 + srow) * D_MODEL + k0 + gch * 8,
                        &As[ci * 512]);
            gload_lds16(W + (size_t)(nBase + ci * 16 + srow) * D_MODEL + k0 + gch * 8,
                        &Ws[ci * 512]);
        }
        __syncthreads();

        bf16x8 af[4], bfr[4];
#pragma unroll
        for (int mt = 0; mt < 4; ++mt)
            af[mt] = *(const bf16x8*)&As[(wm * 64 + mt * 16 + l15) * 32 + (quad ^ swz) * 8];
#pragma unroll
        for (int nt = 0; nt < 4; ++nt)
            bfr[nt] = *(const bf16x8*)&Ws[(wn * 64 + nt * 16 + l15) * 32 + (quad ^ swz) * 8];
#pragma unroll
        for (int mt = 0; mt < 4; ++mt)
#pragma unroll
            for (int nt = 0; nt < 4; ++nt)
                acc[mt][nt] = __builtin_amdgcn_mfma_f32_16x16x32_bf16(af[mt], bfr[nt], acc[mt][nt], 0, 0, 0);
    }

    u16* O = which == 0 ? Qo : (which == 1 ? Ko : Vfo);
    const float scale = which == 0 ? (1.44269504088896f / 64.0f) : 1.0f;
#pragma unroll
    for (int mt = 0; mt < 4; ++mt)
#pragma unroll
        for (int nt = 0; nt < 4; ++nt) {
            const int col = nBase + wn * 64 + nt * 16 + l15;
#pragma unroll
            for (int r = 0; r < 4; ++r) {
                const int row = mBase + wm * 64 + mt * 16 + quad * 4 + r;
                O[(size_t)row * D_MODEL + col] = f2bf(acc[mt][nt][r] * scale);
            }
        }
}

// ---------------------------------------------------------------------------
// O-projection GEMM: Cx(bf16) @ Wo^T + bo -> fp32 out. Same m97 structure.
// ---------------------------------------------------------------------------
__global__ __launch_bounds__(256) void gemm_out(const u16* __restrict__ A,
                                                const u16* __restrict__ W,
                                                const float* __restrict__ bias,
                                                float* __restrict__ C) {
    __shared__ u16 As[8 * 512];
    __shared__ u16 Ws[8 * 512];

    const int nBase = blockIdx.x * 128;
    const int mBase = blockIdx.y * 128;
    const int tid = threadIdx.x, lane = tid & 63, wv = tid >> 6;
    const int l15 = lane & 15, quad = lane >> 4;
    const int wm = wv & 1, wn = wv >> 1;
    const int srow = lane >> 2;
    const int gch  = (lane & 3) ^ ((lane >> 3) & 3);
    const int swz  = (l15 >> 1) & 3;

    floatx4 acc[4][4];
#pragma unroll
    for (int i = 0; i < 4; ++i)
#pragma unroll
        for (int j = 0; j < 4; ++j) acc[i][j] = (floatx4)(0.0f);

    for (int k0 = 0; k0 < D_MODEL; k0 += 32) {
        __syncthreads();
#pragma unroll
        for (int t = 0; t < 2; ++t) {
            const int ci = wv * 2 + t;
            gload_lds16(A + (size_t)(mBase + ci * 16 + srow) * D_MODEL + k0 + gch * 8,
                        &As[ci * 512]);
            gload_lds16(W + (size_t)(nBase + ci * 16 + srow) * D_MODEL + k0 + gch * 8,
                        &Ws[ci * 512]);
        }
        __syncthreads();

        bf16x8 af[4], bfr[4];
#pragma unroll
        for (int mt = 0; mt < 4; ++mt)
            af[mt] = *(const bf16x8*)&As[(wm * 64 + mt * 16 + l15) * 32 + (quad ^ swz) * 8];
#pragma unroll
        for (int nt = 0; nt < 4; ++nt)
            bfr[nt] = *(const bf16x8*)&Ws[(wn * 64 + nt * 16 + l15) * 32 + (quad ^ swz) * 8];
#pragma unroll
        for (int mt = 0; mt < 4; ++mt)
#pragma unroll
            for (int nt = 0; nt < 4; ++nt)
                acc[mt][nt] = __builtin_amdgcn_mfma_f32_16x16x32_bf16(af[mt], bfr[nt], acc[mt][nt], 0, 0, 0);
    }

#pragma unroll
    for (int mt = 0; mt < 4; ++mt)
#pragma unroll
        for (int nt = 0; nt < 4; ++nt) {
            const int col = nBase + wn * 64 + nt * 16 + l15;
            const float bv = bias[col];
#pragma unroll
            for (int r = 0; r < 4; ++r) {
                const int row = mBase + wm * 64 + mt * 16 + quad * 4 + r;
                C[(size_t)row * D_MODEL + col] = acc[mt][nt][r] + bv;
            }
        }
}

// ---------------------------------------------------------------------------
// MFMA flash attention, balanced pairs: block = (pair, h, b) processes q-tiles
// {pair, 31-pair} -> every block does exactly 33 K-tile iterations.
// No max-tracking (logits pre-scaled by log2e/64 in Q, |s| ~ 1 -> exp2 safe;
// masked entries set p=0 directly). Row-sum deferred to end-of-tile reduction.
// K and pre-transposed V staged via global_load_lds into XOR-swizzled LDS.
// ---------------------------------------------------------------------------
__global__ __launch_bounds__(256) void attn2(const u16* __restrict__ Q,
                                             const u16* __restrict__ K,
                                             const u16* __restrict__ Vt,
                                             u16* __restrict__ Ctx) {
    __shared__ u16 Ks[8 * 512];
    __shared__ u16 Vs[8 * 512];
    __shared__ u16 Ps[4][16 * 72];

    const int pair = blockIdx.x;      // 0..15
    const int h = blockIdx.y, b = blockIdx.z;
    const int tid = threadIdx.x, lane = tid & 63, wv = tid >> 6;
    const int l15 = lane & 15, quad = lane >> 4;

    const size_t headOff = ((size_t)b * N_HEADS + h) * S_LEN * HEAD_DIM;
    const u16* Qh = Q + headOff;
    const u16* Kh = K + headOff;
    const u16* Vh = Vt + headOff;     // d-major: [64][2048]
    u16* Cb = Ctx + (size_t)b * S_LEN * D_MODEL + (size_t)h * HEAD_DIM;

    const int srow = lane >> 3;           // 0..7 row within 8-row chunk
    const int gch  = (lane & 7) ^ srow;   // swizzled source chunk
    const int swz  = l15 & 7;             // read-side swizzle

    for (int half = 0; half < 2; ++half) {
        const int qt = half ? (31 - pair) : pair;
        const int qBase = qt * 64;

        bf16x8 qa[2];
#pragma unroll
        for (int ks = 0; ks < 2; ++ks)
            qa[ks] = *(const bf16x8*)(Qh + (size_t)(qBase + wv * 16 + l15) * 64 + ks * 32 + quad * 8);

        floatx4 o[4];
        float lp[4];
#pragma unroll
        for (int r = 0; r < 4; ++r) lp[r] = 0.0f;
#pragma unroll
        for (int nt = 0; nt < 4; ++nt) o[nt] = (floatx4)(0.0f);

        for (int kt = 0; kt <= qt; ++kt) {
            const int kBase = kt * 64;
            __syncthreads();          // prev iteration done reading Ks/Vs
#pragma unroll
            for (int t = 0; t < 2; ++t) {
                const int ci = wv * 2 + t;
                gload_lds16(Kh + (size_t)(kBase + ci * 8 + srow) * 64 + gch * 8, &Ks[ci * 512]);
                gload_lds16(Vh + (size_t)(ci * 8 + srow) * S_LEN + kBase + gch * 8, &Vs[ci * 512]);
            }
            __syncthreads();          // vmcnt(0) drain at barrier

            // S = Q.K^T  (16 queries x 64 keys per wave)
            floatx4 s[4];
#pragma unroll
            for (int nt = 0; nt < 4; ++nt) {
                s[nt] = (floatx4)(0.0f);
#pragma unroll
                for (int ks = 0; ks < 2; ++ks) {
                    const bf16x8 kb = *(const bf16x8*)&Ks[(nt * 16 + l15) * 64 + ((ks * 4 + quad) ^ swz) * 8];
                    s[nt] = __builtin_amdgcn_mfma_f32_16x16x32_bf16(qa[ks], kb, s[nt], 0, 0, 0);
                }
            }

            // softmax numerators (no max tracking); P to LDS in A-layout rows
            if (kt == qt) {
                const int dq = kBase + l15 - (qBase + wv * 16 + quad * 4);
#pragma unroll
                for (int nt = 0; nt < 4; ++nt)
#pragma unroll
                    for (int r = 0; r < 4; ++r) {
                        float p = exp2f(s[nt][r]);
                        p = (dq + nt * 16 > r) ? 0.0f : p;   // causal
                        lp[r] += p;
                        Ps[wv][(quad * 4 + r) * 72 + nt * 16 + l15] =
                            (u16)(__float_as_uint(p) >> 16);
                    }
            } else {
#pragma unroll
                for (int nt = 0; nt < 4; ++nt)
#pragma unroll
                    for (int r = 0; r < 4; ++r) {
                        const float p = exp2f(s[nt][r]);
                        lp[r] += p;
                        Ps[wv][(quad * 4 + r) * 72 + nt * 16 + l15] =
                            (u16)(__float_as_uint(p) >> 16);
                    }
            }

            // O += P.V   (wave-private Ps: in-wave DS ordering, no barrier)
            bf16x8 pa[2];
#pragma unroll
            for (int ks = 0; ks < 2; ++ks)
                pa[ks] = *(const bf16x8*)&Ps[wv][l15 * 72 + ks * 32 + quad * 8];
#pragma unroll
            for (int nt = 0; nt < 4; ++nt)
#pragma unroll
                for (int ks = 0; ks < 2; ++ks) {
                    const bf16x8 vb = *(const bf16x8*)&Vs[(nt * 16 + l15) * 64 + ((ks * 4 + quad) ^ swz) * 8];
                    o[nt] = __builtin_amdgcn_mfma_f32_16x16x32_bf16(pa[ks], vb, o[nt], 0, 0, 0);
                }
        }

        // reduce row sums across l15 lanes, normalize, store
#pragma unroll
        for (int r = 0; r < 4; ++r) {
#pragma unroll
            for (int off = 1; off < 16; off <<= 1) lp[r] += __shfl_xor(lp[r], off);
            const float inv = 1.0f / lp[r];
            const int row = qBase + wv * 16 + quad * 4 + r;
#pragma unroll
            for (int nt = 0; nt < 4; ++nt)
                Cb[(size_t)row * D_MODEL + nt * 16 + l15] = f2bf(o[nt][r] * inv);
        }
    }
}

// ---------------------------------------------------------------------------
extern "C" void kernel_launch(void* const* d_in, const int* in_sizes, int n_in,
                              void* d_out, int out_size, void* d_ws, size_t ws_size,
                              hipStream_t stream) {
    const float* hs = (const float*)d_in[0];
    const float* Wq = (const float*)d_in[1];
    const float* Wk = (const float*)d_in[2];
    const float* Wv = (const float*)d_in[3];
    const float* Wo = (const float*)d_in[4];
    const float* bo = (const float*)d_in[5];
    float* out = (float*)d_out;

    const size_t NHS = (size_t)2 * S_LEN * D_MODEL;  // 4M elements
    const size_t NW  = (size_t)D_MODEL * D_MODEL;    // 1M elements

    u16* hsb = (u16*)d_ws;        // 4M
    u16* Wb  = hsb + NHS;         // 4 x 1M (Wq,Wk,Wv,Wo)
    u16* Qb  = Wb + 4 * NW;       // 4M
    u16* Kb  = Qb + NHS;          // 4M
    u16* Vfb = Kb + NHS;          // 4M (standard projection layout)
    u16* Vtb = Vfb + NHS;         // 4M (per-head transposed [d][s])
    u16* Cxb = Vtb + NHS;         // 4M

    cast_hs<<<2048, 256, 0, stream>>>(hs, hsb);
    cast_w<<<dim3(512, 4), 256, 0, stream>>>(Wq, Wk, Wv, Wo, Wb);

    gemm_qkv<<<dim3(24, 32), 256, 0, stream>>>(hsb, Wb, Wb + NW, Wb + 2 * NW,
                                               Qb, Kb, Vfb);

    vtrans<<<dim3(16, 32), 256, 0, stream>>>(Vfb, Vtb);

    attn2<<<dim3(16, N_HEADS, 2), 256, 0, stream>>>(Qb, Kb, Vtb, Cxb);

    gemm_out<<<dim3(8, 32), 256, 0, stream>>>(Cxb, Wb + 3 * NW, bo, out);
}

// Round 5
// 178.420 us; speedup vs baseline: 7.4399x; 1.1096x over previous
//
#include <hip/hip_runtime.h>

#define S_LEN   2048
#define D_MODEL 1024
#define N_HEADS 16
#define HEAD_DIM 64

typedef unsigned short u16;
typedef float  floatx4 __attribute__((ext_vector_type(4)));
typedef short  bf16x8  __attribute__((ext_vector_type(8)));

__device__ __forceinline__ u16 f2bf(float f) {
    unsigned int u = __float_as_uint(f);
    u += 0x7FFF + ((u >> 16) & 1);      // RNE
    return (u16)(u >> 16);
}
__device__ __forceinline__ unsigned pack2bf(float a, float b) {
    return (unsigned)f2bf(a) | ((unsigned)f2bf(b) << 16);
}

// global -> LDS direct copy, 16B/lane. LDS dest = wave-uniform base + lane*16.
__device__ __forceinline__ void gload_lds16(const void* g, void* l) {
    __builtin_amdgcn_global_load_lds(
        reinterpret_cast<const __attribute__((address_space(1))) unsigned int*>(
            reinterpret_cast<uintptr_t>(g)),
        reinterpret_cast<__attribute__((address_space(3))) unsigned int*>(
            reinterpret_cast<uintptr_t>(l)),
        16, 0, 0);
}

// ---------------------------------------------------------------------------
// Single fused fp32 -> bf16 cast for hs + 4 weights (dst regions contiguous).
// ---------------------------------------------------------------------------
__global__ __launch_bounds__(256) void cast_all(const float* __restrict__ hs,
                                                const float* __restrict__ w0,
                                                const float* __restrict__ w1,
                                                const float* __restrict__ w2,
                                                const float* __restrict__ w3,
                                                u16* __restrict__ dst) {
    const size_t NHS = (size_t)2 * S_LEN * D_MODEL;   // 4M
    const size_t e0 = (size_t)blockIdx.x * 2048;      // block-uniform range
    const float* src;
    size_t base;
    if (e0 < NHS)                 { src = hs; base = 0; }
    else {
        const int wi = (int)((e0 - NHS) >> 20);       // 1M-element weights
        src = wi == 0 ? w0 : wi == 1 ? w1 : wi == 2 ? w2 : w3;
        base = NHS + ((size_t)wi << 20);
    }
    const size_t i = e0 + (size_t)threadIdx.x * 8;
    const float4 a = *(const float4*)(src + (i - base));
    const float4 b = *(const float4*)(src + (i - base) + 4);
    uint4 o;
    o.x = pack2bf(a.x, a.y); o.y = pack2bf(a.z, a.w);
    o.z = pack2bf(b.x, b.y); o.w = pack2bf(b.z, b.w);
    *(uint4*)(dst + i) = o;
}

// ---------------------------------------------------------------------------
// Per-head V transpose (head (b,h) is a CONTIGUOUS (2048 s, 64 d) chunk under
// the module's flat view). Vt[bh][d][s]. Coalesced both sides via LDS.
// ---------------------------------------------------------------------------
__global__ __launch_bounds__(256) void vtrans(const u16* __restrict__ Vf,
                                              u16* __restrict__ Vt) {
    __shared__ unsigned T[64 * 133];
    const int bh = blockIdx.y;            // 0..31
    const int sBase = blockIdx.x * 128;
    const u16* src = Vf + (size_t)bh * (S_LEN * HEAD_DIM) + (size_t)sBase * HEAD_DIM;
    u16* dst = Vt + (size_t)bh * (S_LEN * HEAD_DIM) + sBase;
    const int tid = threadIdx.x;

#pragma unroll
    for (int it = 0; it < 4; ++it) {
        const int idx = it * 256 + tid;
        const int row = idx >> 3, ch = idx & 7;
        const float4 v4 = *(const float4*)(src + row * 64 + ch * 8);
        const u16* vs = (const u16*)&v4;
#pragma unroll
        for (int j = 0; j < 8; ++j) T[(ch * 8 + j) * 133 + row] = vs[j];
    }
    __syncthreads();
#pragma unroll
    for (int it = 0; it < 4; ++it) {
        const int idx = it * 256 + tid;
        const int d = idx >> 4, sc = idx & 15;
        union { u16 u[8]; float4 f; } tmp;
#pragma unroll
        for (int j = 0; j < 8; ++j) tmp.u[j] = (u16)T[d * 133 + sc * 8 + j];
        *(float4*)(dst + (size_t)d * S_LEN + sc * 8) = tmp.f;
    }
}

// ---------------------------------------------------------------------------
// Fused QKV GEMM (m97 structure, 128x128, BK=32, global_load_lds, XOR swizzle).
// Q pre-scaled by log2e/64 (folds logit scaling). Standard (row,col) outputs.
// ---------------------------------------------------------------------------
__global__ __launch_bounds__(256) void gemm_qkv(const u16* __restrict__ A,
                                                const u16* __restrict__ Wq,
                                                const u16* __restrict__ Wk,
                                                const u16* __restrict__ Wv,
                                                u16* __restrict__ Qo,
                                                u16* __restrict__ Ko,
                                                u16* __restrict__ Vfo) {
    __shared__ u16 As[8 * 512];
    __shared__ u16 Ws[8 * 512];

    const int which = blockIdx.x >> 3;
    const int nBase = (blockIdx.x & 7) * 128;
    const int mBase = blockIdx.y * 128;
    const u16* W = which == 0 ? Wq : which == 1 ? Wk : Wv;

    const int tid = threadIdx.x, lane = tid & 63, wv = tid >> 6;
    const int l15 = lane & 15, quad = lane >> 4;
    const int wm = wv & 1, wn = wv >> 1;
    const int srow = lane >> 2;                        // 0..15
    const int gch  = (lane & 3) ^ ((lane >> 3) & 3);   // swizzled src chunk
    const int swz  = (l15 >> 1) & 3;                   // read-side swizzle

    floatx4 acc[4][4];
#pragma unroll
    for (int i = 0; i < 4; ++i)
#pragma unroll
        for (int j = 0; j < 4; ++j) acc[i][j] = (floatx4)(0.0f);

    for (int k0 = 0; k0 < D_MODEL; k0 += 32) {
        __syncthreads();
#pragma unroll
        for (int t = 0; t < 2; ++t) {
            const int ci = wv * 2 + t;
            gload_lds16(A + (size_t)(mBase + ci * 16 + srow) * D_MODEL + k0 + gch * 8,
                        &As[ci * 512]);
            gload_lds16(W + (size_t)(nBase + ci * 16 + srow) * D_MODEL + k0 + gch * 8,
                        &Ws[ci * 512]);
        }
        __syncthreads();

        bf16x8 af[4], bfr[4];
#pragma unroll
        for (int mt = 0; mt < 4; ++mt)
            af[mt] = *(const bf16x8*)&As[(wm * 64 + mt * 16 + l15) * 32 + (quad ^ swz) * 8];
#pragma unroll
        for (int nt = 0; nt < 4; ++nt)
            bfr[nt] = *(const bf16x8*)&Ws[(wn * 64 + nt * 16 + l15) * 32 + (quad ^ swz) * 8];
#pragma unroll
        for (int mt = 0; mt < 4; ++mt)
#pragma unroll
            for (int nt = 0; nt < 4; ++nt)
                acc[mt][nt] = __builtin_amdgcn_mfma_f32_16x16x32_bf16(af[mt], bfr[nt], acc[mt][nt], 0, 0, 0);
    }

    u16* O = which == 0 ? Qo : (which == 1 ? Ko : Vfo);
    const float scale = which == 0 ? (1.44269504088896f / 64.0f) : 1.0f;
#pragma unroll
    for (int mt = 0; mt < 4; ++mt)
#pragma unroll
        for (int nt = 0; nt < 4; ++nt) {
            const int col = nBase + wn * 64 + nt * 16 + l15;
#pragma unroll
            for (int r = 0; r < 4; ++r) {
                const int row = mBase + wm * 64 + mt * 16 + quad * 4 + r;
                O[(size_t)row * D_MODEL + col] = f2bf(acc[mt][nt][r] * scale);
            }
        }
}

// ---------------------------------------------------------------------------
// O-projection GEMM: 64x128 tile (512 blocks -> 2/CU), BK=32, fp32 out + bias.
// ---------------------------------------------------------------------------
__global__ __launch_bounds__(256) void gemm_out(const u16* __restrict__ A,
                                                const u16* __restrict__ W,
                                                const float* __restrict__ bias,
                                                float* __restrict__ C) {
    __shared__ u16 As[4 * 512];
    __shared__ u16 Ws[8 * 512];

    const int nBase = blockIdx.x * 128;
    const int mBase = blockIdx.y * 64;
    const int tid = threadIdx.x, lane = tid & 63, wv = tid >> 6;
    const int l15 = lane & 15, quad = lane >> 4;
    const int wm = wv & 1, wn = wv >> 1;
    const int srow = lane >> 2;
    const int gch  = (lane & 3) ^ ((lane >> 3) & 3);
    const int swz  = (l15 >> 1) & 3;

    floatx4 acc[2][4];
#pragma unroll
    for (int i = 0; i < 2; ++i)
#pragma unroll
        for (int j = 0; j < 4; ++j) acc[i][j] = (floatx4)(0.0f);

    for (int k0 = 0; k0 < D_MODEL; k0 += 32) {
        __syncthreads();
        gload_lds16(A + (size_t)(mBase + wv * 16 + srow) * D_MODEL + k0 + gch * 8,
                    &As[wv * 512]);
#pragma unroll
        for (int t = 0; t < 2; ++t) {
            const int ci = wv * 2 + t;
            gload_lds16(W + (size_t)(nBase + ci * 16 + srow) * D_MODEL + k0 + gch * 8,
                        &Ws[ci * 512]);
        }
        __syncthreads();

        bf16x8 af[2], bfr[4];
#pragma unroll
        for (int mt = 0; mt < 2; ++mt)
            af[mt] = *(const bf16x8*)&As[(wm * 32 + mt * 16 + l15) * 32 + (quad ^ swz) * 8];
#pragma unroll
        for (int nt = 0; nt < 4; ++nt)
            bfr[nt] = *(const bf16x8*)&Ws[(wn * 64 + nt * 16 + l15) * 32 + (quad ^ swz) * 8];
#pragma unroll
        for (int mt = 0; mt < 2; ++mt)
#pragma unroll
            for (int nt = 0; nt < 4; ++nt)
                acc[mt][nt] = __builtin_amdgcn_mfma_f32_16x16x32_bf16(af[mt], bfr[nt], acc[mt][nt], 0, 0, 0);
    }

#pragma unroll
    for (int mt = 0; mt < 2; ++mt)
#pragma unroll
        for (int nt = 0; nt < 4; ++nt) {
            const int col = nBase + wn * 64 + nt * 16 + l15;
            const float bv = bias[col];
#pragma unroll
            for (int r = 0; r < 4; ++r) {
                const int row = mBase + wm * 32 + mt * 16 + quad * 4 + r;
                C[(size_t)row * D_MODEL + col] = acc[mt][nt][r] + bv;
            }
        }
}

// ---------------------------------------------------------------------------
// MFMA flash attention v3.
//  - 1D grid 512, XCD-locality swizzle: all 16 pair-blocks of one (b,h) share
//    flat%8 -> same XCD L2 caches that head's K/V once (fixes 8x over-fetch).
//  - S^T = K.Q^T (swapped MFMA operands): lane holds P[query=l15][key=quad*4+r]
//    -> 4 consecutive addresses -> v_perm pack + ds_write_b64 (was 16 b16).
//  - lp is one scalar per lane (query=l15); reduced once per q-tile.
//  - Double-buffered K/V staging via global_load_lds, ONE barrier per K-tile.
// ---------------------------------------------------------------------------
__global__ __launch_bounds__(256) void attn3(const u16* __restrict__ Q,
                                             const u16* __restrict__ K,
                                             const u16* __restrict__ Vt,
                                             u16* __restrict__ Ctx) {
    __shared__ u16 Ks[2][8 * 512];
    __shared__ u16 Vs[2][8 * 512];
    __shared__ u16 Ps[4][16 * 72];

    const int flat = blockIdx.x;
    const int g    = (flat & 7) | ((flat >> 7) << 3);   // 0..31  (b*16+h)
    const int pair = (flat >> 3) & 15;
    const int h = g & 15, b = g >> 4;

    const int tid = threadIdx.x, lane = tid & 63, wv = tid >> 6;
    const int l15 = lane & 15, quad = lane >> 4;

    const size_t headOff = ((size_t)b * N_HEADS + h) * S_LEN * HEAD_DIM;
    const u16* Qh = Q + headOff;
    const u16* Kh = K + headOff;
    const u16* Vh = Vt + headOff;     // d-major: [64][2048]
    u16* Cb = Ctx + (size_t)b * S_LEN * D_MODEL + (size_t)h * HEAD_DIM;

    const int srow = lane >> 3;           // 0..7 row within 8-row chunk
    const int gch  = (lane & 7) ^ srow;   // swizzled source chunk
    const int swz  = l15 & 7;             // read-side swizzle

    for (int half = 0; half < 2; ++half) {
        const int qt = half ? (31 - pair) : pair;
        const int qBase = qt * 64;

        bf16x8 qa[2];
#pragma unroll
        for (int ks = 0; ks < 2; ++ks)
            qa[ks] = *(const bf16x8*)(Qh + (size_t)(qBase + wv * 16 + l15) * 64 + ks * 32 + quad * 8);

        floatx4 o[4];
#pragma unroll
        for (int nt = 0; nt < 4; ++nt) o[nt] = (floatx4)(0.0f);
        float lp = 0.0f;

        __syncthreads();                  // prev half's readers done with buf 0
        // prologue: stage tile 0 into buf 0
#pragma unroll
        for (int t = 0; t < 2; ++t) {
            const int ci = wv * 2 + t;
            gload_lds16(Kh + (size_t)(ci * 8 + srow) * 64 + gch * 8, &Ks[0][ci * 512]);
            gload_lds16(Vh + (size_t)(ci * 8 + srow) * S_LEN + gch * 8, &Vs[0][ci * 512]);
        }

        int cur = 0;
        for (int kt = 0; kt <= qt; ++kt) {
            __syncthreads();              // drains vmcnt -> buf cur valid
            if (kt < qt) {
                const int nb = (kt + 1) * 64;
#pragma unroll
                for (int t = 0; t < 2; ++t) {
                    const int ci = wv * 2 + t;
                    gload_lds16(Kh + (size_t)(nb + ci * 8 + srow) * 64 + gch * 8,
                                &Ks[cur ^ 1][ci * 512]);
                    gload_lds16(Vh + (size_t)(ci * 8 + srow) * S_LEN + nb + gch * 8,
                                &Vs[cur ^ 1][ci * 512]);
                }
            }

            // S^T = K.Q^T : A = K tile (64 keys), B = wave's 16 queries
            floatx4 s[4];
#pragma unroll
            for (int mt = 0; mt < 4; ++mt) {
                s[mt] = (floatx4)(0.0f);
#pragma unroll
                for (int ks = 0; ks < 2; ++ks) {
                    const bf16x8 kb = *(const bf16x8*)&Ks[cur][(mt * 16 + l15) * 64 + ((ks * 4 + quad) ^ swz) * 8];
                    s[mt] = __builtin_amdgcn_mfma_f32_16x16x32_bf16(kb, qa[ks], s[mt], 0, 0, 0);
                }
            }

            // p = exp2(s) (Q pre-scaled by log2e/64); causal on diag tile.
            // lane holds P[query=l15][key=mt*16+quad*4+r] -> pack 4 -> b64.
            const bool diag = (kt == qt);
#pragma unroll
            for (int mt = 0; mt < 4; ++mt) {
                float p[4];
#pragma unroll
                for (int r = 0; r < 4; ++r) {
                    float pv = exp2f(s[mt][r]);
                    if (diag && (mt * 16 + quad * 4 + r > wv * 16 + l15)) pv = 0.0f;
                    p[r] = pv;
                    lp += pv;
                }
                uint2 w;
                w.x = __builtin_amdgcn_perm(__float_as_uint(p[1]), __float_as_uint(p[0]), 0x07060302);
                w.y = __builtin_amdgcn_perm(__float_as_uint(p[3]), __float_as_uint(p[2]), 0x07060302);
                *(uint2*)&Ps[wv][l15 * 72 + mt * 16 + quad * 4] = w;
            }

            // O += P.V  (wave-private Ps: in-wave DS ordering)
            bf16x8 pa[2];
#pragma unroll
            for (int ks = 0; ks < 2; ++ks)
                pa[ks] = *(const bf16x8*)&Ps[wv][l15 * 72 + ks * 32 + quad * 8];
#pragma unroll
            for (int nt = 0; nt < 4; ++nt)
#pragma unroll
                for (int ks = 0; ks < 2; ++ks) {
                    const bf16x8 vb = *(const bf16x8*)&Vs[cur][(nt * 16 + l15) * 64 + ((ks * 4 + quad) ^ swz) * 8];
                    o[nt] = __builtin_amdgcn_mfma_f32_16x16x32_bf16(pa[ks], vb, o[nt], 0, 0, 0);
                }
            cur ^= 1;
        }

        // row sums: lanes with same l15 hold partials -> 2 shfls
        lp += __shfl_xor(lp, 16);
        lp += __shfl_xor(lp, 32);

#pragma unroll
        for (int r = 0; r < 4; ++r) {
            const float inv = 1.0f / __shfl(lp, quad * 4 + r);   // lane (l15=quad*4+r)
            const int row = qBase + wv * 16 + quad * 4 + r;
#pragma unroll
            for (int nt = 0; nt < 4; ++nt)
                Cb[(size_t)row * D_MODEL + nt * 16 + l15] = f2bf(o[nt][r] * inv);
        }
    }
}

// ---------------------------------------------------------------------------
extern "C" void kernel_launch(void* const* d_in, const int* in_sizes, int n_in,
                              void* d_out, int out_size, void* d_ws, size_t ws_size,
                              hipStream_t stream) {
    const float* hs = (const float*)d_in[0];
    const float* Wq = (const float*)d_in[1];
    const float* Wk = (const float*)d_in[2];
    const float* Wv = (const float*)d_in[3];
    const float* Wo = (const float*)d_in[4];
    const float* bo = (const float*)d_in[5];
    float* out = (float*)d_out;

    const size_t NHS = (size_t)2 * S_LEN * D_MODEL;  // 4M elements
    const size_t NW  = (size_t)D_MODEL * D_MODEL;    // 1M elements

    u16* hsb = (u16*)d_ws;        // 4M
    u16* Wb  = hsb + NHS;         // 4 x 1M (Wq,Wk,Wv,Wo) — contiguous with hsb
    u16* Qb  = Wb + 4 * NW;       // 4M
    u16* Kb  = Qb + NHS;          // 4M
    u16* Vfb = Kb + NHS;          // 4M (standard projection layout)
    u16* Vtb = Vfb + NHS;         // 4M (per-head transposed [d][s])
    u16* Cxb = Vtb + NHS;         // 4M

    cast_all<<<4096, 256, 0, stream>>>(hs, Wq, Wk, Wv, Wo, hsb);

    gemm_qkv<<<dim3(24, 32), 256, 0, stream>>>(hsb, Wb, Wb + NW, Wb + 2 * NW,
                                               Qb, Kb, Vfb);

    vtrans<<<dim3(16, 32), 256, 0, stream>>>(Vfb, Vtb);

    attn3<<<512, 256, 0, stream>>>(Qb, Kb, Vtb, Cxb);

    gemm_out<<<dim3(8, 64), 256, 0, stream>>>(Cxb, Wb + 3 * NW, bo, out);
}